// Round 8
// baseline (122.039 us; speedup 1.0000x reference)
//
#include <hip/hip_runtime.h>
#include <math.h>

// (B,P,V,F,H) = (32,512,32,16,64). Round 8: split each bp across TWO waves
// (wave u owns output cols 32u..32u+31) to break the round-5/7 latency
// plateau: per-wave serial chain and register state halve, wave count
// doubles (32768 waves -> up to 8/SIMD). Weights stay pre-packed in d_ws as
// bf16 MFMA B-frags (36 KB, L1-resident, VMEM pipe). The x-buffer is now
// wave-SHARED (layerK A-frags span both column halves) => 3 __syncthreads
// per bp (2-wave block, cheap). LDS 4.7 KB/block.
// MFMA 16x16x32 bf16: A[m=lane&15][k=quad*8+j], B[k=quad*8+j][n=lane&15],
//                     D[row=quad*4+reg][col=lane&15]  (verified rounds 2-7).
namespace {
constexpr int kXS = 72;
constexpr float kSlope = 0.01f;

typedef short bf16x8 __attribute__((ext_vector_type(8)));
typedef float f32x4  __attribute__((ext_vector_type(4)));

__device__ __forceinline__ float lrelu(float x) { return fmaxf(x, kSlope * x); }

// round-to-nearest-even f32->bf16, branch-free (inputs finite here).
__device__ __forceinline__ unsigned short bfrne(float a) {
    union { float f; unsigned u; } v; v.f = a;
    return (unsigned short)((v.u + 0x7FFFu + ((v.u >> 16) & 1u)) >> 16);
}

// ---- pre-pass: pack W1/W2/W3 as bf16 MFMA B-frags into d_ws ----
// frag f: 0..3 = W1 (nt=f, K=16 zero-padded); 4..19 = W2 (nt=(f-4)>>2,
// ks=(f-4)&3); 20..35 = W3. Lane l of frag f lives at ws[f*512 + l*8 ..+7].
__global__ void prep_weights(const float* __restrict__ W1,
                             const float* __restrict__ W2,
                             const float* __restrict__ W3,
                             unsigned short* __restrict__ ws)
{
    int t = blockIdx.x * blockDim.x + threadIdx.x;
    if (t >= 36 * 64) return;
    int f = t >> 6, l = t & 63, c = l & 15, q = l >> 4;
    unsigned short v[8] = {0, 0, 0, 0, 0, 0, 0, 0};
    const float* src = nullptr; int row = 0, k0 = 0, K = 0;
    if (f < 4) {
        if (q < 2) { src = W1; row = 16 * f + c; k0 = q * 8; K = 16; }
    } else if (f < 20) {
        int g = f - 4;  src = W2; row = 16 * (g >> 2) + c; k0 = (g & 3) * 32 + q * 8; K = 128;
    } else {
        int g = f - 20; src = W3; row = 16 * (g >> 2) + c; k0 = (g & 3) * 32 + q * 8; K = 128;
    }
    if (src) {
        #pragma unroll
        for (int j = 0; j < 8; ++j) v[j] = bfrne(src[row * K + k0 + j]);
    }
    unsigned short* dst = ws + (size_t)f * 512 + l * 8;
    *(ushort4*)(dst)     = make_ushort4(v[0], v[1], v[2], v[3]);
    *(ushort4*)(dst + 4) = make_ushort4(v[4], v[5], v[6], v[7]);
}

__global__ __launch_bounds__(128, 6) void fused_mlp_v8(
    const float* __restrict__ X, const int* __restrict__ M,
    const unsigned short* __restrict__ WF,
    const float* __restrict__ B1, const float* __restrict__ B2,
    const float* __restrict__ B3, float* __restrict__ OUT)
{
    __shared__ __align__(16) short xb[32 * kXS];  // 4608 B, shared by both waves
    __shared__ __align__(16) short pl[64];        //  128 B

    const int t = threadIdx.x, u = t >> 6, l = t & 63, c = l & 15, q = l >> 4;
    const size_t bp = (size_t)blockIdx.x;
    const int nb = 32 * u;                        // this wave's col base

    // ---- inputs for this bp (both waves load the same rows; L1 dedups) ----
    float4 xr[2][2];
    if (q < 2) {
        #pragma unroll
        for (int mt = 0; mt < 2; ++mt) {
            const float4* p = (const float4*)(X + (bp * 32 + 16 * mt + c) * 16 + q * 8);
            xr[mt][0] = p[0]; xr[mt][1] = p[1];
        }
    }
    const int4* Mp = (const int4*)(M + bp * 32);
    const int4 mr0 = Mp[q], mr1 = Mp[4 + q];
    const unsigned mbits =
        (mr0.x ? 1u : 0u)  | (mr0.y ? 2u : 0u)  | (mr0.z ? 4u : 0u)  | (mr0.w ? 8u : 0u) |
        (mr1.x ? 16u : 0u) | (mr1.y ? 32u : 0u) | (mr1.z ? 64u : 0u) | (mr1.w ? 128u : 0u);
    const bool anyv = __any(mbits != 0);

    f32x4 acc[2][2];   // [mt][nt], nt local to this wave's 32-col half

    // ---- layer 1 (K=16 zero-padded to 32); W1 frags 2u+nt from WF ----
    {
        bf16x8 a1f[2];
        #pragma unroll
        for (int mt = 0; mt < 2; ++mt) {
            bf16x8 v = {};
            if (q < 2) {
                float4 f0 = xr[mt][0], f1 = xr[mt][1];
                v[0] = (short)bfrne(f0.x); v[1] = (short)bfrne(f0.y);
                v[2] = (short)bfrne(f0.z); v[3] = (short)bfrne(f0.w);
                v[4] = (short)bfrne(f1.x); v[5] = (short)bfrne(f1.y);
                v[6] = (short)bfrne(f1.z); v[7] = (short)bfrne(f1.w);
            }
            a1f[mt] = v;
        }
        #pragma unroll
        for (int nt = 0; nt < 2; ++nt) {
            float b = B1[nb + 16 * nt + c];
            bf16x8 wf = *(const bf16x8*)(WF + (size_t)(2 * u + nt) * 512 + l * 8);
            f32x4 c0 = { b, b, b, b };
            acc[0][nt] = __builtin_amdgcn_mfma_f32_16x16x32_bf16(a1f[0], wf, c0, 0, 0, 0);
            acc[1][nt] = __builtin_amdgcn_mfma_f32_16x16x32_bf16(a1f[1], wf, c0, 0, 0, 0);
        }
    }

    // ---- epilogue: lrelu/mask, b16 writes to shared xb, pool -> pl ----
    auto epilogue = [&]() {
        float pool[2];
        #pragma unroll
        for (int nt = 0; nt < 2; ++nt) {
            float pv = -INFINITY;
            #pragma unroll
            for (int mt = 0; mt < 2; ++mt) {
                short* base = &xb[(16 * mt + 4 * q) * kXS + nb + 16 * nt + c];
                #pragma unroll
                for (int r = 0; r < 4; ++r) {
                    float y = lrelu(acc[mt][nt][r]);
                    bool mk = (mbits >> (mt * 4 + r)) & 1;
                    float o = mk ? y : 0.f;
                    pv = mk ? fmaxf(pv, y) : pv;
                    base[r * kXS] = (short)bfrne(o);
                }
            }
            pv = fmaxf(pv, __shfl_xor(pv, 16));
            pv = fmaxf(pv, __shfl_xor(pv, 32));
            pool[nt] = anyv ? pv : 0.f;
        }
        if (q < 2) pl[nb + 16 * q + c] = (short)bfrne(q ? pool[1] : pool[0]);
    };

    // ---- K=128 layer: A-frags span BOTH col halves (shared xb/pl) ----
    auto layerK = [&](int fb, const float* __restrict__ Bv) {
        bf16x8 a00 = *(const bf16x8*)&xb[(     c) * kXS      + q * 8];
        bf16x8 a01 = *(const bf16x8*)&xb[(16 + c) * kXS      + q * 8];
        bf16x8 a10 = *(const bf16x8*)&xb[(     c) * kXS + 32 + q * 8];
        bf16x8 a11 = *(const bf16x8*)&xb[(16 + c) * kXS + 32 + q * 8];
        bf16x8 ap0 = *(const bf16x8*)&pl[q * 8];        // quad-broadcast
        bf16x8 ap1 = *(const bf16x8*)&pl[32 + q * 8];
        #pragma unroll
        for (int nt = 0; nt < 2; ++nt) {
            float b = Bv[nb + 16 * nt + c];
            acc[0][nt] = f32x4{ b, b, b, b };
            acc[1][nt] = acc[0][nt];
        }
        #pragma unroll
        for (int ks = 0; ks < 4; ++ks) {
            bf16x8 am0 = (ks == 0) ? a00 : (ks == 1) ? a10 : (ks == 2) ? ap0 : ap1;
            bf16x8 am1 = (ks == 0) ? a01 : (ks == 1) ? a11 : (ks == 2) ? ap0 : ap1;
            #pragma unroll
            for (int nt = 0; nt < 2; ++nt) {
                int f = fb + (2 * u + nt) * 4 + ks;
                bf16x8 wf = *(const bf16x8*)(WF + (size_t)f * 512 + l * 8);
                acc[0][nt] = __builtin_amdgcn_mfma_f32_16x16x32_bf16(am0, wf, acc[0][nt], 0, 0, 0);
                acc[1][nt] = __builtin_amdgcn_mfma_f32_16x16x32_bf16(am1, wf, acc[1][nt], 0, 0, 0);
            }
        }
    };

    epilogue();            // x2 = [out1 | pool1]
    __syncthreads();       // writes visible to partner wave
    layerK(4, B2);         // layer 2
    __syncthreads();       // partner's reads done before overwrite (WAR)
    epilogue();            // x3 in place
    __syncthreads();       // writes visible
    layerK(20, B3);        // layer 3

    // ---- layer-3 pool == final output ----
    #pragma unroll
    for (int nt = 0; nt < 2; ++nt) {
        float pv = -INFINITY;
        #pragma unroll
        for (int mt = 0; mt < 2; ++mt)
            #pragma unroll
            for (int r = 0; r < 4; ++r) {
                bool mk = (mbits >> (mt * 4 + r)) & 1;
                float y = lrelu(acc[mt][nt][r]);
                pv = mk ? fmaxf(pv, y) : pv;
            }
        pv = fmaxf(pv, __shfl_xor(pv, 16));
        pv = fmaxf(pv, __shfl_xor(pv, 32));
        pv = anyv ? pv : 0.f;
        if (q == 0) OUT[bp * 64 + nb + 16 * nt + c] = pv;
    }
}
} // namespace

extern "C" void kernel_launch(void* const* d_in, const int* in_sizes, int n_in,
                              void* d_out, int out_size, void* d_ws, size_t ws_size,
                              hipStream_t stream) {
    (void)in_sizes; (void)n_in; (void)ws_size; (void)out_size;
    const float* X  = (const float*)d_in[0];
    const int*   M  = (const int*)d_in[1];
    const float* W1 = (const float*)d_in[2];
    const float* B1 = (const float*)d_in[3];
    const float* W2 = (const float*)d_in[4];
    const float* B2 = (const float*)d_in[5];
    const float* W3 = (const float*)d_in[6];
    const float* B3 = (const float*)d_in[7];
    float* OUT = (float*)d_out;
    unsigned short* WF = (unsigned short*)d_ws;   // needs 36 KB of scratch

    prep_weights<<<(36 * 64 + 255) / 256, 256, 0, stream>>>(W1, W2, W3, WF);
    // 16384 blocks x 2 waves; one bp per block, each wave owns 32 output cols
    fused_mlp_v8<<<16384, 128, 0, stream>>>(X, M, WF, B1, B2, B3, OUT);
}